// Round 5
// baseline (51124.475 us; speedup 1.0000x reference)
//
#include <hip/hip_runtime.h>

// ---------------------------------------------------------------------------
// HiPPO-LSTM, B=32, S=2048, D=512, H=512, N=256, G=2048.
//
// Fully-fused sequential kernel (64 persistent blocks, 1 device barrier/step):
//   gates = x_t·Wx^T + h·Whh^T + hippo·Wn^T   (all via bf16 MFMA, split ops:
//     x,h paths: hi/lo Ootomo 3-pass; hippo path: hi/mid/lo 6-pass)
//   elementwise LSTM in fp64; S_f[b] = h·wbar + beta in fp64
//   barrier; closed-form fp64 hippo update (state in registers).
//
// R8 (de-risked R7: container failed twice on R7 — suspect the inline-asm
// dwordx4 loads (no early-clobber + spill-race with ~420 live VGPRs).
// Revert to R6's proven 8B __hip_atomic_load h-prefetch and drop the
// Whh-hi register hoist; keep the five low-risk R7 changes):
//   * hippo fp64 state hip_d: LDS -> registers hn[32]. Kills its 4-way
//     b64 bank conflicts (3.5e8/dispatch measured) and fp64 LDS traffic.
//   * fast branchless fp64 exp (deg-11 poly, ~1e-14 rel) for sigm/tanh.
//   * float-domain hi/mi/lo split in hippo update (~2x cheaper).
//   * cell state in register (was LDS).
//   * out[] NT stores after the arrival-flag store: HBM ack drains under
//     the poll window, off the h-critical chain.
//   Kept from R6: flag-array barrier (no RMW, wave-parallel poll),
//   sc1-only exchange (no fence anywhere), xpass under poll, segment
//   sums under poll, hippo-W frags (nB) in regs, h-prefetch before
//   hippo MFMA chain.
// ---------------------------------------------------------------------------

#define B_ 32
#define S_ 2048
#define D_ 512
#define H_ 512
#define NH_ 256
#define G_ 2048
#define KW 2816          // WREC row: hh_hi 512|hh_lo 512|xw_hi 512|xw_lo 512|nw_hi 256|nw_mid 256|nw_lo 256
#define NBLK 64
#define JPB 8
#define MAXS 1000.0

typedef __attribute__((ext_vector_type(8))) short short8;
typedef __attribute__((ext_vector_type(4))) float f32x4;

// ws layout (bytes)
#define CNT_OFF   0ULL
#define SFP_OFF   256ULL                       // double[2][64][32] = 32768
#define HB_OFF    33024ULL                     // ushort[2][32][1024] = 131072 (hi|lo planes)
#define STATE_BYTES 164096ULL
#define XBH_OFF   164096ULL                    // ushort[32][2048][512] = 67108864
#define XBL_OFF   67272960ULL                  // ushort[32][2048][512] = 67108864
#define WREC_OFF  134381824ULL                 // ushort[2048][2816] = 11534336
#define ARR_OFF   145916160ULL                 // uint[64*64] arrival flags, 256B stride = 16384
// total 145932544 bytes (~139.2 MiB)

#define AL(p)    __hip_atomic_load((p), __ATOMIC_RELAXED, __HIP_MEMORY_SCOPE_AGENT)
#define AS(p, v) __hip_atomic_store((p), (v), __ATOMIC_RELAXED, __HIP_MEMORY_SCOPE_AGENT)

__device__ __forceinline__ unsigned short f2b(float f) {
  unsigned u = __float_as_uint(f);
  unsigned r = (u + 0x7fffu + ((u >> 16) & 1u)) >> 16;
  return (unsigned short)r;
}
__device__ __forceinline__ float b2f(unsigned short s) {
  return __uint_as_float(((unsigned)s) << 16);
}

// branchless fp64 exp, ~1e-14 rel on clamped range (gate pre-activations
// are |x|<~30; tanh arg 2*c may be huge -> clamp saturates correctly).
__device__ __forceinline__ double exp_d(double x) {
  x = fmin(fmax(x, -708.0), 709.0);
  double t = x * 1.4426950408889634074;
  double n = __builtin_rint(t);
  double r = fma(n, -0.693147180559945286227, x);
  r = fma(n, -2.3190468138462995584e-17, r);
  double p = 2.7557319223985890653e-7;          // 1/10!
  p = fma(p, r, 2.7557319223985888276e-6);      // 1/9!
  p = fma(p, r, 2.4801587301587301566e-5);      // 1/8!
  p = fma(p, r, 1.9841269841269841253e-4);      // 1/7!
  p = fma(p, r, 1.3888888888888889418e-3);      // 1/6!
  p = fma(p, r, 8.3333333333333332177e-3);      // 1/5!
  p = fma(p, r, 4.1666666666666664354e-2);      // 1/4!
  p = fma(p, r, 1.6666666666666665741e-1);      // 1/3!
  p = fma(p, r, 5.0e-1);
  p = fma(p, r, 1.0);
  p = fma(p, r, 1.0);
  long long bits = ((long long)(int)n + 1023ll) << 52;
  return p * __longlong_as_double(bits);
}
__device__ __forceinline__ double sigm_d(double x) { return 1.0 / (1.0 + exp_d(-x)); }
__device__ __forceinline__ double tanh_d(double x) {
  double e = exp_d(2.0 * x);                     // clamped -> finite
  return 1.0 - 2.0 / (e + 1.0);
}
__device__ __forceinline__ short8 mk8(unsigned long long a, unsigned long long b) {
  union { unsigned long long q[2]; short8 s; } u;
  u.q[0] = a; u.q[1] = b;
  return u.s;
}

// ---------------- prep kernels ----------------
__global__ __launch_bounds__(256) void k_cvt2(const float* __restrict__ in,
                                              unsigned short* __restrict__ hi,
                                              unsigned short* __restrict__ lo, size_t n) {
  size_t i = (size_t)blockIdx.x * blockDim.x + threadIdx.x;
  size_t stride = (size_t)gridDim.x * blockDim.x;
  for (; i < n; i += stride) {
    float v = in[i];
    unsigned short h = f2b(v);
    hi[i] = h;
    lo[i] = f2b(v - b2f(h));
  }
}

__global__ __launch_bounds__(256) void k_wrec2(const float* __restrict__ Whh,
                                               const float* __restrict__ Wih,
                                               unsigned short* __restrict__ out) {
  size_t i = (size_t)blockIdx.x * 256 + threadIdx.x;   // over 2048*2816
  if (i >= (size_t)G_ * KW) return;
  int gb = (int)(i / KW), k = (int)(i % KW);
  int blk = gb >> 5, c = gb & 31;
  int grow = (c >> 3) * H_ + blk * JPB + (c & 7);      // gate*512 + hidden index
  unsigned short v;
  if (k < 512) {                                        // Whh hi
    v = f2b(Whh[(size_t)grow * 512 + k]);
  } else if (k < 1024) {                                // Whh lo
    float w = Whh[(size_t)grow * 512 + (k - 512)];
    v = f2b(w - b2f(f2b(w)));
  } else if (k < 1536) {                                // Wih-x hi
    v = f2b(Wih[(size_t)grow * 768 + (k - 1024)]);
  } else if (k < 2048) {                                // Wih-x lo
    float w = Wih[(size_t)grow * 768 + (k - 1536)];
    v = f2b(w - b2f(f2b(w)));
  } else if (k < 2304) {                                // Wih-hippo hi
    v = f2b(Wih[(size_t)grow * 768 + 512 + (k - 2048)]);
  } else if (k < 2560) {                                // Wih-hippo mid
    float w = Wih[(size_t)grow * 768 + 512 + (k - 2304)];
    v = f2b(w - b2f(f2b(w)));
  } else {                                              // Wih-hippo lo
    float w = Wih[(size_t)grow * 768 + 512 + (k - 2560)];
    float h1 = b2f(f2b(w));
    float m1 = b2f(f2b(w - h1));
    v = f2b(w - h1 - m1);
  }
  out[i] = v;
}

// ---------------- persistent sequential kernel ----------------
__global__ __launch_bounds__(256, 1) void k_seq(const unsigned short* __restrict__ XBH,
                                                const unsigned short* __restrict__ XBL,
                                                const unsigned short* __restrict__ WREC,
                                                const float* __restrict__ Wh2h,
                                                const float* __restrict__ bh2h,
                                                const float* __restrict__ bih,
                                                const float* __restrict__ bhh,
                                                float* __restrict__ out,
                                                unsigned short* __restrict__ HB,
                                                double* __restrict__ SfP,
                                                unsigned* __restrict__ arr) {
  const int blk = blockIdx.x, tid = threadIdx.x;

  __shared__ unsigned short hip_hi[32][264];   // bf16 hi/mid/lo for MFMA A-frags
  __shared__ unsigned short hip_mi[32][264];
  __shared__ unsigned short hip_lo[32][264];
  __shared__ float gat_xh[32][33];             // x+h MFMA partial
  __shared__ float gat_n[32][33];              // hippo MFMA partial
  __shared__ double segw[32][8], segu[32][8];
  __shared__ double sfl[32];
  __shared__ double stabd[256];

  for (int i = tid; i < 32 * 264; i += 256) {
    (&hip_hi[0][0])[i] = 0; (&hip_mi[0][0])[i] = 0; (&hip_lo[0][0])[i] = 0;
  }
  stabd[tid] = sqrt(2.0 * (double)tid + 1.0);

  // elementwise roles
  const int eb = tid >> 3, ej = tid & 7;
  const int jg = blk * JPB + ej;

  // per-thread invariants (fp64): wbar, sbeta; cell state in register
  double wreg = 0.0, sbeta = 0.0;
  for (int n = 0; n < NH_; ++n) {
    wreg += (double)Wh2h[(size_t)n * H_ + jg];
    sbeta += (double)bh2h[n];
  }
  double creg = 0.0;

  // fp64 hippo state in registers: thread (hb,hs) owns n = hs*32 .. +31 of batch hb
  const int hb = tid & 31, hs = tid >> 5;
  double hn[32];
#pragma unroll
  for (int i = 0; i < 32; ++i) hn[i] = 0.0;
  __syncthreads();

  // MFMA roles (4 waves)
  const int w = tid >> 6, l = tid & 63;
  const int lb = l & 15, lq = l >> 4;
  const int mt = w & 1, nt = w >> 1;
  const int bA = mt * 16 + lb;         // batch row for A frags
  const int cB = nt * 16 + lb;         // local gate col for B frags
  const unsigned short* wrow = WREC + ((size_t)(blk * 32 + cB)) * KW + lq * 8;
  // per-thread gate biases (fp64)
  const double bi0 = (double)bih[0 * 512 + jg] + (double)bhh[0 * 512 + jg];
  const double bi1 = (double)bih[1 * 512 + jg] + (double)bhh[1 * 512 + jg];
  const double bi2 = (double)bih[2 * 512 + jg] + (double)bhh[2 * 512 + jg];
  const double bi3 = (double)bih[3 * 512 + jg] + (double)bhh[3 * 512 + jg];

  // Hippo-path B fragments are loop-invariant: hoist into registers once
  // (24 short8 = 96 VGPR, live for all 2048 steps).
  short8 nB[24];
#pragma unroll
  for (int kt = 0; kt < 8; ++kt) {
    nB[kt * 3 + 0] = *(const short8*)(wrow + 2048 + kt * 32);
    nB[kt * 3 + 1] = *(const short8*)(wrow + 2304 + kt * 32);
    nB[kt * 3 + 2] = *(const short8*)(wrow + 2560 + kt * 32);
  }

  // x-path MFMA (Ootomo 3-pass, K=512); runs under the barrier wait for t+1
  auto xpass = [&](int tt) -> f32x4 {
    f32x4 a = {0.f, 0.f, 0.f, 0.f};
    const unsigned short* xh = XBH + ((size_t)bA * S_ + tt) * D_ + lq * 8;
    const unsigned short* xl = XBL + ((size_t)bA * S_ + tt) * D_ + lq * 8;
#pragma unroll
    for (int kt = 0; kt < 16; ++kt) {
      short8 ah = *(const short8*)(xh + kt * 32);
      short8 al = *(const short8*)(xl + kt * 32);
      short8 bh = *(const short8*)(wrow + 1024 + kt * 32);
      short8 bl = *(const short8*)(wrow + 1536 + kt * 32);
      a = __builtin_amdgcn_mfma_f32_16x16x32_bf16(ah, bh, a, 0, 0, 0);
      a = __builtin_amdgcn_mfma_f32_16x16x32_bf16(ah, bl, a, 0, 0, 0);
      a = __builtin_amdgcn_mfma_f32_16x16x32_bf16(al, bh, a, 0, 0, 0);
    }
    return a;
  };
  f32x4 axx = xpass(0);   // prologue: x-path for t=0

  for (int t = 0; t < S_; ++t) {
    const int wslot = t & 1, rslot = wslot ^ 1;

    // ---- h-plane prefetch: 64x 8B sc1 loads, issued before hippo MFMA ----
    const unsigned long long* hq =
        (const unsigned long long*)(HB + (size_t)rslot * (B_ * 1024) + (size_t)bA * 1024 + lq * 8);
    unsigned long long hA[64];
#pragma unroll
    for (int kt = 0; kt < 16; ++kt) {
      hA[kt * 2 + 0]      = AL(hq + kt * 8 + 0);        // hi plane
      hA[kt * 2 + 1]      = AL(hq + kt * 8 + 1);
      hA[32 + kt * 2 + 0] = AL(hq + 128 + kt * 8 + 0);  // lo plane
      hA[32 + kt * 2 + 1] = AL(hq + 128 + kt * 8 + 1);
    }

    // ---- hippo path MFMA: hi/mid/lo, 6 passes, K=256 (covers hA latency) ----
    f32x4 an = {0.f, 0.f, 0.f, 0.f};
#pragma unroll
    for (int kt = 0; kt < 8; ++kt) {
      short8 ah = *(const short8*)(&hip_hi[bA][kt * 32 + lq * 8]);
      short8 am = *(const short8*)(&hip_mi[bA][kt * 32 + lq * 8]);
      short8 al = *(const short8*)(&hip_lo[bA][kt * 32 + lq * 8]);
      an = __builtin_amdgcn_mfma_f32_16x16x32_bf16(ah, nB[kt * 3 + 0], an, 0, 0, 0);
      an = __builtin_amdgcn_mfma_f32_16x16x32_bf16(ah, nB[kt * 3 + 1], an, 0, 0, 0);
      an = __builtin_amdgcn_mfma_f32_16x16x32_bf16(am, nB[kt * 3 + 0], an, 0, 0, 0);
      an = __builtin_amdgcn_mfma_f32_16x16x32_bf16(ah, nB[kt * 3 + 2], an, 0, 0, 0);
      an = __builtin_amdgcn_mfma_f32_16x16x32_bf16(am, nB[kt * 3 + 1], an, 0, 0, 0);
      an = __builtin_amdgcn_mfma_f32_16x16x32_bf16(al, nB[kt * 3 + 0], an, 0, 0, 0);
    }
    // h path: hi/lo Ootomo 3-pass, K=512 (A-frags from prefetched regs),
    // chained onto the prefetched x accumulator
    f32x4 axh = axx;
#pragma unroll
    for (int kt = 0; kt < 16; ++kt) {
      short8 ah = mk8(hA[kt * 2 + 0], hA[kt * 2 + 1]);
      short8 al = mk8(hA[32 + kt * 2 + 0], hA[32 + kt * 2 + 1]);
      short8 bh = *(const short8*)(wrow + kt * 32);
      short8 bl = *(const short8*)(wrow + 512 + kt * 32);
      axh = __builtin_amdgcn_mfma_f32_16x16x32_bf16(ah, bh, axh, 0, 0, 0);
      axh = __builtin_amdgcn_mfma_f32_16x16x32_bf16(ah, bl, axh, 0, 0, 0);
      axh = __builtin_amdgcn_mfma_f32_16x16x32_bf16(al, bh, axh, 0, 0, 0);
    }
#pragma unroll
    for (int r = 0; r < 4; ++r) {
      gat_xh[mt * 16 + lq * 4 + r][cB] = axh[r];
      gat_n[mt * 16 + lq * 4 + r][cB] = an[r];
    }
    __syncthreads();

    // ---- elementwise LSTM (fp64, fast exp, cell state in register) ----
    double h_out;
    {
      double pi = (double)gat_xh[eb][0 * 8 + ej] + (double)gat_n[eb][0 * 8 + ej] + bi0;
      double pf = (double)gat_xh[eb][1 * 8 + ej] + (double)gat_n[eb][1 * 8 + ej] + bi1;
      double pg = (double)gat_xh[eb][2 * 8 + ej] + (double)gat_n[eb][2 * 8 + ej] + bi2;
      double po = (double)gat_xh[eb][3 * 8 + ej] + (double)gat_n[eb][3 * 8 + ej] + bi3;
      double c = sigm_d(pf) * creg + sigm_d(pi) * tanh_d(pg);
      creg = c;
      double h = sigm_d(po) * tanh_d(c);
      h_out = h;
      float hf = (float)h;
      unsigned short hh = f2b(hf);
      unsigned short hl = f2b((float)(h - (double)b2f(hh)));
      unsigned short* hb_w = HB + (size_t)wslot * (B_ * 1024) + (size_t)eb * 1024;
      AS(hb_w + jg, hh);
      AS(hb_w + 512 + jg, hl);
      // partial S_f (fp64)
      double part = h * wreg;
      part += __shfl_down(part, 4, 64);
      part += __shfl_down(part, 2, 64);
      part += __shfl_down(part, 1, 64);
      if (ej == 0) AS(SfP + (size_t)wslot * (NBLK * B_) + blk * B_ + eb, part);
    }
    __syncthreads();   // compiler vmcnt(0): HB/SfP sc1 stores L3-acked here

    const size_t oidx = (size_t)eb * (S_ * H_) + (size_t)t * H_ + jg;
    if (t == S_ - 1) {
      __builtin_nontemporal_store((float)h_out, &out[oidx]);
      __builtin_nontemporal_store((float)creg, &out[(size_t)B_ * S_ * H_ + oidx]);
      break;
    }

    // -------- device barrier: per-block flags, RELAXED store (no wbl2) --------
    if (tid == 0) AS(&arr[(size_t)blk * 64], (unsigned)(t + 1));

    // out stores drain during the poll window (off the h-critical chain)
    __builtin_nontemporal_store((float)h_out, &out[oidx]);
    __builtin_nontemporal_store((float)creg, &out[(size_t)B_ * S_ * H_ + oidx]);

    // ---- x-path MFMA for t+1, hidden under the barrier wait ----
    axx = xpass(t + 1);

    // ---- hippo segment sums from register state ----
    {
      double sw = 0.0, su = 0.0;
#pragma unroll
      for (int i = 0; i < 32; ++i) {
        double hv = hn[i];
        sw += stabd[hs * 32 + i] * hv;
        su += hv;
      }
      segw[hb][hs] = sw;
      segu[hb][hs] = su;
    }

    if (tid < 64) {
      unsigned* ap = arr + (size_t)tid * 64;
      const unsigned target = (unsigned)(t + 1);
      while (AL(ap) < target) {}
    }
    __syncthreads();

    // ---- S_f reduce (fp64, sc1 loads) ----
    {
      const double* sp = SfP + (size_t)wslot * (NBLK * B_) + eb;
      double v = 0.0;
#pragma unroll
      for (int m = 0; m < 8; ++m) v += AL(sp + (size_t)(ej * 8 + m) * B_);
      v += __shfl_down(v, 4, 64);
      v += __shfl_down(v, 2, 64);
      v += __shfl_down(v, 1, 64);
      if (ej == 0) sfl[eb] = v + sbeta;
    }
    __syncthreads();

    // ---- hippo closed-form update (fp64 regs, float-domain hi/mi/lo split) ----
    {
      double U = 0.0, Sh = 0.0;
#pragma unroll
      for (int s2 = 0; s2 < 8; ++s2) {
        Sh += segu[hb][s2];
        if (s2 < hs) U += segw[hb][s2];
      }
      const double Sf = sfl[hb];
      const double inv = 0.5 / (double)(t + 1);
#pragma unroll
      for (int i = 0; i < 32; ++i) {
        const int n = hs * 32 + i;
        double hv = hn[i];
        double vv = Sh + inv * (stabd[n] * (Sf - U) - (double)(n + 1) * hv);
        vv = fmin(fmax(vv, -MAXS), MAXS);
        hn[i] = vv;
        float vf = (float)vv;
        unsigned short vh = f2b(vf);
        double rem = vv - (double)b2f(vh);
        float rf = (float)rem;
        unsigned short vm = f2b(rf);
        hip_hi[hb][n] = vh;
        hip_mi[hb][n] = vm;
        hip_lo[hb][n] = f2b(rf - b2f(vm));
        U += stabd[n] * hv;
      }
    }
    __syncthreads();
  }
}

extern "C" void kernel_launch(void* const* d_in, const int* in_sizes, int n_in,
                              void* d_out, int out_size, void* d_ws, size_t ws_size,
                              hipStream_t stream) {
  const float* x    = (const float*)d_in[0];
  const float* Wih  = (const float*)d_in[1];
  const float* Whh  = (const float*)d_in[2];
  const float* bih  = (const float*)d_in[3];
  const float* bhh  = (const float*)d_in[4];
  const float* Wh2h = (const float*)d_in[5];
  const float* bh2h = (const float*)d_in[6];
  float* out = (float*)d_out;
  char* ws = (char*)d_ws;

  double* SfP          = (double*)(ws + SFP_OFF);
  unsigned short* HB   = (unsigned short*)(ws + HB_OFF);
  unsigned short* XBH  = (unsigned short*)(ws + XBH_OFF);
  unsigned short* XBL  = (unsigned short*)(ws + XBL_OFF);
  unsigned short* WREC = (unsigned short*)(ws + WREC_OFF);
  unsigned* arr        = (unsigned*)(ws + ARR_OFF);

  hipMemsetAsync(ws, 0, STATE_BYTES, stream);
  hipMemsetAsync(ws + ARR_OFF, 0, 16384, stream);
  k_cvt2<<<8192, 256, 0, stream>>>(x, XBH, XBL, (size_t)B_ * S_ * D_);
  k_wrec2<<<((size_t)G_ * KW + 255) / 256, 256, 0, stream>>>(Whh, Wih, WREC);
  k_seq<<<NBLK, 256, 0, stream>>>(XBH, XBL, WREC, Wh2h, bh2h, bih, bhh, out, HB, SfP, arr);
}

// Round 6
// 37171.060 us; speedup vs baseline: 1.3754x; 1.3754x over previous
//
#include <hip/hip_runtime.h>

// ---------------------------------------------------------------------------
// HiPPO-LSTM, B=32, S=2048, D=512, H=512, N=256, G=2048.
//
// R9 structure:
//   PRE:  k_wrec2 packs weights; k_xg computes XG = x·Wx^T for ALL (b,t)
//         as a massively-parallel MFMA GEMM (bit-identical Ootomo 3-pass,
//         same kt order as the old in-loop xpass). Layout
//         XG[t][blk][b][ej][g] -> per (block,step) a contiguous 4KB blob.
//   SEQ:  k_seq per step: load x-accumulator C-frags from XG (plain cached
//         loads), chain h-path MFMAs onto it (bit-identical to streaming
//         version), hippo-path MFMA, fp64 LSTM elementwise, sc1 h/Sf
//         exchange, flag-array barrier, closed-form fp64 hippo update.
//   The x-path (48 chained MFMAs + 1.2GB streaming) is thereby removed
//   from wave0's pre-poll critical path in the sequential kernel.
//   Also: hippo bf16 plane writes packed into ds_write_b128 (12 instead of
//   96 conflicted b16 writes per thread per step).
//   Kept from R5/R3: flag-array barrier (no RMW, wave-parallel poll),
//   sc1-only exchange (no fence anywhere), h-prefetch before hippo MFMA,
//   segment sums under the poll window, nB weight frags in registers,
//   fp64 reg hippo state, fast fp64 exp, packed hi/mi/lo split.
// ---------------------------------------------------------------------------

#define B_ 32
#define S_ 2048
#define D_ 512
#define H_ 512
#define NH_ 256
#define G_ 2048
#define KW 2816          // WREC row: hh_hi 512|hh_lo 512|xw_hi 512|xw_lo 512|nw_hi 256|nw_mid 256|nw_lo 256
#define NBLK 64
#define JPB 8
#define MAXS 1000.0

typedef __attribute__((ext_vector_type(8))) short short8;
typedef __attribute__((ext_vector_type(4))) float f32x4;

// ws layout (bytes)
#define SFP_OFF   256ULL                       // double[2][64][32] = 32768
#define HB_OFF    33024ULL                     // ushort[2][32][1024] = 131072 (hi|lo planes)
#define ARR_OFF   164096ULL                    // uint[64*64] arrival flags, 256B stride = 16384
#define STATE_BYTES 180480ULL
#define WREC_OFF  180480ULL                    // ushort[2048][2816] = 11534336
#define XG_OFF    11714816ULL                  // float[2048][64][32][32] = 536870912
// total 548585728 bytes (~523.2 MiB)

#define AL(p)    __hip_atomic_load((p), __ATOMIC_RELAXED, __HIP_MEMORY_SCOPE_AGENT)
#define AS(p, v) __hip_atomic_store((p), (v), __ATOMIC_RELAXED, __HIP_MEMORY_SCOPE_AGENT)

__device__ __forceinline__ unsigned short f2b(float f) {
  unsigned u = __float_as_uint(f);
  unsigned r = (u + 0x7fffu + ((u >> 16) & 1u)) >> 16;
  return (unsigned short)r;
}
__device__ __forceinline__ float b2f(unsigned short s) {
  return __uint_as_float(((unsigned)s) << 16);
}

// branchless fp64 exp, ~1e-14 rel on clamped range
__device__ __forceinline__ double exp_d(double x) {
  x = fmin(fmax(x, -708.0), 709.0);
  double t = x * 1.4426950408889634074;
  double n = __builtin_rint(t);
  double r = fma(n, -0.693147180559945286227, x);
  r = fma(n, -2.3190468138462995584e-17, r);
  double p = 2.7557319223985890653e-7;
  p = fma(p, r, 2.7557319223985888276e-6);
  p = fma(p, r, 2.4801587301587301566e-5);
  p = fma(p, r, 1.9841269841269841253e-4);
  p = fma(p, r, 1.3888888888888889418e-3);
  p = fma(p, r, 8.3333333333333332177e-3);
  p = fma(p, r, 4.1666666666666664354e-2);
  p = fma(p, r, 1.6666666666666665741e-1);
  p = fma(p, r, 5.0e-1);
  p = fma(p, r, 1.0);
  p = fma(p, r, 1.0);
  long long bits = ((long long)(int)n + 1023ll) << 52;
  return p * __longlong_as_double(bits);
}
__device__ __forceinline__ double sigm_d(double x) { return 1.0 / (1.0 + exp_d(-x)); }
__device__ __forceinline__ double tanh_d(double x) {
  double e = exp_d(2.0 * x);
  return 1.0 - 2.0 / (e + 1.0);
}
__device__ __forceinline__ short8 mk8(unsigned long long a, unsigned long long b) {
  union { unsigned long long q[2]; short8 s; } u;
  u.q[0] = a; u.q[1] = b;
  return u.s;
}

// ---------------- prep kernels ----------------
__global__ __launch_bounds__(256) void k_wrec2(const float* __restrict__ Whh,
                                               const float* __restrict__ Wih,
                                               unsigned short* __restrict__ out) {
  size_t i = (size_t)blockIdx.x * 256 + threadIdx.x;   // over 2048*2816
  if (i >= (size_t)G_ * KW) return;
  int gb = (int)(i / KW), k = (int)(i % KW);
  int blk = gb >> 5, c = gb & 31;
  int grow = (c >> 3) * H_ + blk * JPB + (c & 7);      // gate*512 + hidden index
  unsigned short v;
  if (k < 512) {                                        // Whh hi
    v = f2b(Whh[(size_t)grow * 512 + k]);
  } else if (k < 1024) {                                // Whh lo
    float w = Whh[(size_t)grow * 512 + (k - 512)];
    v = f2b(w - b2f(f2b(w)));
  } else if (k < 1536) {                                // Wih-x hi
    v = f2b(Wih[(size_t)grow * 768 + (k - 1024)]);
  } else if (k < 2048) {                                // Wih-x lo
    float w = Wih[(size_t)grow * 768 + (k - 1536)];
    v = f2b(w - b2f(f2b(w)));
  } else if (k < 2304) {                                // Wih-hippo hi
    v = f2b(Wih[(size_t)grow * 768 + 512 + (k - 2048)]);
  } else if (k < 2560) {                                // Wih-hippo mid
    float w = Wih[(size_t)grow * 768 + 512 + (k - 2304)];
    v = f2b(w - b2f(f2b(w)));
  } else {                                              // Wih-hippo lo
    float w = Wih[(size_t)grow * 768 + 512 + (k - 2560)];
    float h1 = b2f(f2b(w));
    float m1 = b2f(f2b(w - h1));
    v = f2b(w - h1 - m1);
  }
  out[i] = v;
}

// XG[t][blk][b][ej][g] = x-path gate partials, MFMA-accumulated exactly as
// the old in-loop xpass (same split, same kt order, C starts at 0).
__global__ __launch_bounds__(256) void k_xg(const float* __restrict__ x,
                                            const unsigned short* __restrict__ WREC,
                                            float* __restrict__ XG) {
  const int bid = blockIdx.x;
  const int t = bid >> 6, blk = bid & 63;
  const int tid = threadIdx.x;
  const int w = tid >> 6, l = tid & 63;
  const int lb = l & 15, lq = l >> 4;
  const int mt = w & 1, nt = w >> 1;
  const int bA = mt * 16 + lb;
  const int cB = nt * 16 + lb;
  const unsigned short* wrow = WREC + ((size_t)(blk * 32 + cB)) * KW + lq * 8;
  const float* xrow = x + ((size_t)bA * S_ + t) * D_ + lq * 8;
  f32x4 a = {0.f, 0.f, 0.f, 0.f};
#pragma unroll
  for (int kt = 0; kt < 16; ++kt) {
    f32x4 xv0 = *(const f32x4*)(xrow + kt * 32);
    f32x4 xv1 = *(const f32x4*)(xrow + kt * 32 + 4);
    short8 ah, al;
#pragma unroll
    for (int e = 0; e < 4; ++e) {
      float v0 = xv0[e], v1 = xv1[e];
      unsigned short h0 = f2b(v0), h1 = f2b(v1);
      ah[e] = (short)h0;     ah[e + 4] = (short)h1;
      al[e] = (short)f2b(v0 - b2f(h0));
      al[e + 4] = (short)f2b(v1 - b2f(h1));
    }
    short8 bh = *(const short8*)(wrow + 1024 + kt * 32);
    short8 bl = *(const short8*)(wrow + 1536 + kt * 32);
    a = __builtin_amdgcn_mfma_f32_16x16x32_bf16(ah, bh, a, 0, 0, 0);
    a = __builtin_amdgcn_mfma_f32_16x16x32_bf16(ah, bl, a, 0, 0, 0);
    a = __builtin_amdgcn_mfma_f32_16x16x32_bf16(al, bh, a, 0, 0, 0);
  }
  float* blob = XG + (size_t)bid * 1024;
  const int coff = (cB & 7) * 4 + (cB >> 3);
#pragma unroll
  for (int r = 0; r < 4; ++r)
    blob[(mt * 16 + lq * 4 + r) * 32 + coff] = a[r];
}

// ---------------- persistent sequential kernel ----------------
__global__ __launch_bounds__(256, 1) void k_seq(const float* __restrict__ XG,
                                                const unsigned short* __restrict__ WREC,
                                                const float* __restrict__ Wh2h,
                                                const float* __restrict__ bh2h,
                                                const float* __restrict__ bih,
                                                const float* __restrict__ bhh,
                                                float* __restrict__ out,
                                                unsigned short* __restrict__ HB,
                                                double* __restrict__ SfP,
                                                unsigned* __restrict__ arr) {
  const int blk = blockIdx.x, tid = threadIdx.x;

  __shared__ unsigned short hip_hi[32][264];   // bf16 hi/mid/lo for MFMA A-frags
  __shared__ unsigned short hip_mi[32][264];
  __shared__ unsigned short hip_lo[32][264];
  __shared__ float gat_xh[32][33];             // x+h MFMA partial
  __shared__ float gat_n[32][33];              // hippo MFMA partial
  __shared__ double segw[32][8], segu[32][8];
  __shared__ double sfl[32];
  __shared__ double stabd[256];

  for (int i = tid; i < 32 * 264; i += 256) {
    (&hip_hi[0][0])[i] = 0; (&hip_mi[0][0])[i] = 0; (&hip_lo[0][0])[i] = 0;
  }
  stabd[tid] = sqrt(2.0 * (double)tid + 1.0);

  // elementwise roles
  const int eb = tid >> 3, ej = tid & 7;
  const int jg = blk * JPB + ej;

  // per-thread invariants (fp64)
  double wreg = 0.0, sbeta = 0.0;
  for (int n = 0; n < NH_; ++n) {
    wreg += (double)Wh2h[(size_t)n * H_ + jg];
    sbeta += (double)bh2h[n];
  }
  double creg = 0.0;

  // fp64 hippo state in registers: thread (hb,hs) owns n = hs*32 .. +31 of batch hb
  const int hb = tid & 31, hs = tid >> 5;
  double hn[32];
#pragma unroll
  for (int i = 0; i < 32; ++i) hn[i] = 0.0;
  __syncthreads();

  // MFMA roles (4 waves)
  const int w = tid >> 6, l = tid & 63;
  const int lb = l & 15, lq = l >> 4;
  const int mt = w & 1, nt = w >> 1;
  const int bA = mt * 16 + lb;         // batch row for A frags
  const int cB = nt * 16 + lb;         // local gate col for B frags
  const unsigned short* wrow = WREC + ((size_t)(blk * 32 + cB)) * KW + lq * 8;
  const int coff = (cB & 7) * 4 + (cB >> 3);        // col offset in XG blob
  // per-thread gate biases (fp64)
  const double bi0 = (double)bih[0 * 512 + jg] + (double)bhh[0 * 512 + jg];
  const double bi1 = (double)bih[1 * 512 + jg] + (double)bhh[1 * 512 + jg];
  const double bi2 = (double)bih[2 * 512 + jg] + (double)bhh[2 * 512 + jg];
  const double bi3 = (double)bih[3 * 512 + jg] + (double)bhh[3 * 512 + jg];

  // Hippo-path B fragments: loop-invariant, in registers for all 2048 steps
  short8 nB[24];
#pragma unroll
  for (int kt = 0; kt < 8; ++kt) {
    nB[kt * 3 + 0] = *(const short8*)(wrow + 2048 + kt * 32);
    nB[kt * 3 + 1] = *(const short8*)(wrow + 2304 + kt * 32);
    nB[kt * 3 + 2] = *(const short8*)(wrow + 2560 + kt * 32);
  }

  for (int t = 0; t < S_; ++t) {
    const int wslot = t & 1, rslot = wslot ^ 1;

    // ---- x-accumulator C-frags from XG (plain cached loads) ----
    const float* xgb = XG + ((size_t)t * 64 + blk) * 1024;
    f32x4 axh;
#pragma unroll
    for (int r = 0; r < 4; ++r)
      axh[r] = xgb[(mt * 16 + lq * 4 + r) * 32 + coff];

    // ---- h-plane prefetch: 64x 8B sc1 loads, issued before hippo MFMA ----
    const unsigned long long* hq =
        (const unsigned long long*)(HB + (size_t)rslot * (B_ * 1024) + (size_t)bA * 1024 + lq * 8);
    unsigned long long hA[64];
#pragma unroll
    for (int kt = 0; kt < 16; ++kt) {
      hA[kt * 2 + 0]      = AL(hq + kt * 8 + 0);        // hi plane
      hA[kt * 2 + 1]      = AL(hq + kt * 8 + 1);
      hA[32 + kt * 2 + 0] = AL(hq + 128 + kt * 8 + 0);  // lo plane
      hA[32 + kt * 2 + 1] = AL(hq + 128 + kt * 8 + 1);
    }

    // ---- hippo path MFMA: hi/mid/lo, 6 passes, K=256 (covers load latency) ----
    f32x4 an = {0.f, 0.f, 0.f, 0.f};
#pragma unroll
    for (int kt = 0; kt < 8; ++kt) {
      short8 ah = *(const short8*)(&hip_hi[bA][kt * 32 + lq * 8]);
      short8 am = *(const short8*)(&hip_mi[bA][kt * 32 + lq * 8]);
      short8 al = *(const short8*)(&hip_lo[bA][kt * 32 + lq * 8]);
      an = __builtin_amdgcn_mfma_f32_16x16x32_bf16(ah, nB[kt * 3 + 0], an, 0, 0, 0);
      an = __builtin_amdgcn_mfma_f32_16x16x32_bf16(ah, nB[kt * 3 + 1], an, 0, 0, 0);
      an = __builtin_amdgcn_mfma_f32_16x16x32_bf16(am, nB[kt * 3 + 0], an, 0, 0, 0);
      an = __builtin_amdgcn_mfma_f32_16x16x32_bf16(ah, nB[kt * 3 + 2], an, 0, 0, 0);
      an = __builtin_amdgcn_mfma_f32_16x16x32_bf16(am, nB[kt * 3 + 1], an, 0, 0, 0);
      an = __builtin_amdgcn_mfma_f32_16x16x32_bf16(al, nB[kt * 3 + 0], an, 0, 0, 0);
    }
    // h path: hi/lo Ootomo 3-pass, K=512, chained onto loaded x accumulator
    // (bit-identical to the old streamed xpass handoff)
#pragma unroll
    for (int kt = 0; kt < 16; ++kt) {
      short8 ah = mk8(hA[kt * 2 + 0], hA[kt * 2 + 1]);
      short8 al = mk8(hA[32 + kt * 2 + 0], hA[32 + kt * 2 + 1]);
      short8 bh = *(const short8*)(wrow + kt * 32);
      short8 bl = *(const short8*)(wrow + 512 + kt * 32);
      axh = __builtin_amdgcn_mfma_f32_16x16x32_bf16(ah, bh, axh, 0, 0, 0);
      axh = __builtin_amdgcn_mfma_f32_16x16x32_bf16(ah, bl, axh, 0, 0, 0);
      axh = __builtin_amdgcn_mfma_f32_16x16x32_bf16(al, bh, axh, 0, 0, 0);
    }
#pragma unroll
    for (int r = 0; r < 4; ++r) {
      gat_xh[mt * 16 + lq * 4 + r][cB] = axh[r];
      gat_n[mt * 16 + lq * 4 + r][cB] = an[r];
    }
    __syncthreads();

    // ---- elementwise LSTM (fp64, fast exp, cell state in register) ----
    double h_out;
    {
      double pi = (double)gat_xh[eb][0 * 8 + ej] + (double)gat_n[eb][0 * 8 + ej] + bi0;
      double pf = (double)gat_xh[eb][1 * 8 + ej] + (double)gat_n[eb][1 * 8 + ej] + bi1;
      double pg = (double)gat_xh[eb][2 * 8 + ej] + (double)gat_n[eb][2 * 8 + ej] + bi2;
      double po = (double)gat_xh[eb][3 * 8 + ej] + (double)gat_n[eb][3 * 8 + ej] + bi3;
      double c = sigm_d(pf) * creg + sigm_d(pi) * tanh_d(pg);
      creg = c;
      double h = sigm_d(po) * tanh_d(c);
      h_out = h;
      float hf = (float)h;
      unsigned short hh = f2b(hf);
      unsigned short hl = f2b((float)(h - (double)b2f(hh)));
      unsigned short* hb_w = HB + (size_t)wslot * (B_ * 1024) + (size_t)eb * 1024;
      AS(hb_w + jg, hh);
      AS(hb_w + 512 + jg, hl);
      // partial S_f (fp64)
      double part = h * wreg;
      part += __shfl_down(part, 4, 64);
      part += __shfl_down(part, 2, 64);
      part += __shfl_down(part, 1, 64);
      if (ej == 0) AS(SfP + (size_t)wslot * (NBLK * B_) + blk * B_ + eb, part);
    }
    __syncthreads();   // compiler vmcnt(0): HB/SfP sc1 stores L3-acked here

    const size_t oidx = (size_t)eb * (S_ * H_) + (size_t)t * H_ + jg;
    if (t == S_ - 1) {
      __builtin_nontemporal_store((float)h_out, &out[oidx]);
      __builtin_nontemporal_store((float)creg, &out[(size_t)B_ * S_ * H_ + oidx]);
      break;
    }

    // -------- device barrier: per-block flags, RELAXED store (no wbl2) --------
    if (tid == 0) AS(&arr[(size_t)blk * 64], (unsigned)(t + 1));

    // out stores drain during the poll window (off the h-critical chain)
    __builtin_nontemporal_store((float)h_out, &out[oidx]);
    __builtin_nontemporal_store((float)creg, &out[(size_t)B_ * S_ * H_ + oidx]);

    // ---- hippo segment sums from register state (under the wait) ----
    {
      double sw = 0.0, su = 0.0;
#pragma unroll
      for (int i = 0; i < 32; ++i) {
        double hv = hn[i];
        sw += stabd[hs * 32 + i] * hv;
        su += hv;
      }
      segw[hb][hs] = sw;
      segu[hb][hs] = su;
    }

    if (tid < 64) {
      unsigned* ap = arr + (size_t)tid * 64;
      const unsigned target = (unsigned)(t + 1);
      while (AL(ap) < target) {}
    }
    __syncthreads();

    // ---- S_f reduce (fp64, sc1 loads) ----
    {
      const double* sp = SfP + (size_t)wslot * (NBLK * B_) + eb;
      double v = 0.0;
#pragma unroll
      for (int m = 0; m < 8; ++m) v += AL(sp + (size_t)(ej * 8 + m) * B_);
      v += __shfl_down(v, 4, 64);
      v += __shfl_down(v, 2, 64);
      v += __shfl_down(v, 1, 64);
      if (ej == 0) sfl[eb] = v + sbeta;
    }
    __syncthreads();

    // ---- hippo closed-form update (fp64 regs, packed b128 LDS writes) ----
    {
      double U = 0.0, Sh = 0.0;
#pragma unroll
      for (int s2 = 0; s2 < 8; ++s2) {
        Sh += segu[hb][s2];
        if (s2 < hs) U += segw[hb][s2];
      }
      const double Sf = sfl[hb];
      const double inv = 0.5 / (double)(t + 1);
#pragma unroll
      for (int k8 = 0; k8 < 4; ++k8) {
        short8 ph, pm, pl;
#pragma unroll
        for (int j = 0; j < 8; ++j) {
          const int i = k8 * 8 + j;
          const int n = hs * 32 + i;
          double hv = hn[i];
          double vv = Sh + inv * (stabd[n] * (Sf - U) - (double)(n + 1) * hv);
          vv = fmin(fmax(vv, -MAXS), MAXS);
          hn[i] = vv;
          float vf = (float)vv;
          unsigned short vh = f2b(vf);
          double rem = vv - (double)b2f(vh);
          float rf = (float)rem;
          unsigned short vm = f2b(rf);
          ph[j] = (short)vh;
          pm[j] = (short)vm;
          pl[j] = (short)f2b(rf - b2f(vm));
          U += stabd[n] * hv;
        }
        *(short8*)&hip_hi[hb][hs * 32 + k8 * 8] = ph;
        *(short8*)&hip_mi[hb][hs * 32 + k8 * 8] = pm;
        *(short8*)&hip_lo[hb][hs * 32 + k8 * 8] = pl;
      }
    }
    __syncthreads();
  }
}

extern "C" void kernel_launch(void* const* d_in, const int* in_sizes, int n_in,
                              void* d_out, int out_size, void* d_ws, size_t ws_size,
                              hipStream_t stream) {
  const float* x    = (const float*)d_in[0];
  const float* Wih  = (const float*)d_in[1];
  const float* Whh  = (const float*)d_in[2];
  const float* bih  = (const float*)d_in[3];
  const float* bhh  = (const float*)d_in[4];
  const float* Wh2h = (const float*)d_in[5];
  const float* bh2h = (const float*)d_in[6];
  float* out = (float*)d_out;
  char* ws = (char*)d_ws;

  double* SfP          = (double*)(ws + SFP_OFF);
  unsigned short* HB   = (unsigned short*)(ws + HB_OFF);
  unsigned* arr        = (unsigned*)(ws + ARR_OFF);
  unsigned short* WREC = (unsigned short*)(ws + WREC_OFF);
  float* XG            = (float*)(ws + XG_OFF);

  hipMemsetAsync(ws, 0, STATE_BYTES, stream);
  k_wrec2<<<((size_t)G_ * KW + 255) / 256, 256, 0, stream>>>(Whh, Wih, WREC);
  k_xg<<<S_ * NBLK, 256, 0, stream>>>(x, WREC, XG);
  k_seq<<<NBLK, 256, 0, stream>>>(XG, WREC, Wh2h, bh2h, bih, bhh, out, HB, SfP, arr);
}